// Round 1
// 249.889 us; speedup vs baseline: 1.3092x; 1.3092x over previous
//
#include <hip/hip_runtime.h>

#define H 8
#define NSEQ 4096
#define DIM 64
#define BATCH 8
#define AREV_LEN 4384   // 4096 lags + 288 zero pad (max read idx 4373). 4384 elems =
                        // 2192 dwords == 16 mod 32 -> lds1 sits at bank offset +16 vs
                        // lds0: parity groups hit disjoint bank halves.
#define XPLEN 4144      // 16 front zeros (shifted-col reads) + 4096 + 32 tail pad
                        // (prefetch overrun). 8288 B/row, 16B-aligned.
#define HD (H*DIM)      // 512

typedef __attribute__((ext_vector_type(8))) short short8;
typedef __attribute__((ext_vector_type(4))) float float4v;

__device__ inline unsigned short f32_to_bf16(float f) {
    unsigned int u = __float_as_uint(f);
    u += 0x7fffu + ((u >> 16) & 1u);   // RNE
    return (unsigned short)(u >> 16);
}

// ---- P1: arev[hd][i] = bf16( exp(clamp(log(gamma)*k + pos[k-1])) ) at k = 4095 - i ----
// (k==0 uses `zero`). Block (kb,h) also zeroes the pad of row d=kb (replaces memset).
__global__ __launch_bounds__(256) void build_arev(
    const float* __restrict__ zero, const float* __restrict__ pos,
    const float* __restrict__ gamma, unsigned short* __restrict__ arev)
{
    __shared__ float lg[64];
    __shared__ unsigned short T[64][65];
    int h = blockIdx.y, kb = blockIdx.x;
    int tid = threadIdx.x;
    if (tid < 64) lg[tid] = logf(gamma[h*64 + tid]);
    __syncthreads();
    #pragma unroll
    for (int jj = 0; jj < 16; ++jj) {
        int e = tid + 256*jj;
        int kk = e >> 6, dd = e & 63;
        int k = kb*64 + kk;
        float v;
        if (k == 0) v = zero[h*64 + dd];
        else        v = lg[dd] * (float)k + pos[(h*4095 + (k-1))*64 + dd];
        v = fminf(30.f, fmaxf(-60.f, v));
        T[kk][dd] = f32_to_bf16(expf(v));
    }
    __syncthreads();
    int i0 = 4032 - kb*64;   // tile writes arev[hd][i0 .. i0+63], i = 4095 - k
    #pragma unroll
    for (int jj = 0; jj < 16; ++jj) {
        int e = tid + 256*jj;
        int dpr = e >> 6, ii = e & 63;
        arev[(size_t)(h*64 + dpr)*AREV_LEN + i0 + ii] = T[63 - ii][dpr];
    }
    // zero pad region [4096, AREV_LEN) of row d = kb
    unsigned short* pr = arev + (size_t)(h*64 + kb)*AREV_LEN + 4096;
    for (int i = tid; i < AREV_LEN - 4096; i += 256) pr[i] = 0;
}

// ---- P2: xp[hd][b][16 + s] = bf16(x[b][h][s][d]); rows front/tail zero-padded ----
__global__ __launch_bounds__(256) void build_xp(
    const float* __restrict__ x, unsigned short* __restrict__ xp)
{
    __shared__ unsigned short T[64][65];
    int sb = blockIdx.x, h = blockIdx.y, b = blockIdx.z;
    int tid = threadIdx.x;
    const float* src = x + ((size_t)(b*H + h)*NSEQ + sb*64)*DIM;
    #pragma unroll
    for (int jj = 0; jj < 16; ++jj) {
        int e = tid + 256*jj;
        int ss = e >> 6, dd = e & 63;
        T[ss][dd] = f32_to_bf16(src[ss*64 + dd]);
    }
    __syncthreads();
    #pragma unroll
    for (int jj = 0; jj < 16; ++jj) {
        int e = tid + 256*jj;
        int dpr = e >> 6, ii = e & 63;
        xp[((size_t)(h*64 + dpr)*BATCH + b)*XPLEN + 16 + sb*64 + ii] = T[ii][dpr];
    }
    if (sb == 0) {
        for (int e = tid; e < 64*16; e += 256) {
            int dd = e >> 4, i = e & 15;
            xp[((size_t)(h*64 + dd)*BATCH + b)*XPLEN + i] = 0;
        }
    }
    if (sb == 63) {
        for (int e = tid; e < 64*32; e += 256) {
            int dd = e >> 5, i = e & 31;
            xp[((size_t)(h*64 + dd)*BATCH + b)*XPLEN + 16 + NSEQ + i] = 0;
        }
    }
}

// ---- GEMM: per (h,d): Out[t, 0:8] = sum_s a[t-s] * X[s, 0:8], causal ----
// One WG = one (h,d) and a 1024-row t-band. 4 waves; wave w owns band
// [T0+256w, T0+256w+256): MFMA cols 0-7 (batches, x unshifted) produce the odd
// 16-row strips at t-base b=T0+256w+16+32j; cols 8-15 (same batches, x shifted
// -16 via front pad) produce the even strips at b-16+32j -- all 16 MFMA columns
// useful, zero extra k-steps. A-fragments rotate through an 8-slot ring with
// COMPILE-TIME indices (manual 8-step unroll; trip count is always a multiple
// of 8) so the rotation is pure register renaming, not v_movs.
__global__ __launch_bounds__(256) void toeplitz_gemm(
    const unsigned short* __restrict__ arev,
    const unsigned short* __restrict__ xp,
    float* __restrict__ out)
{
    __shared__ unsigned short lds[2*AREV_LEN];   // [0]: arev, [AREV_LEN]: arev shifted +1

    // swizzle: 16 line-sharing consecutive-d WGs -> same XCD (id%8); big t-tiles first.
    int id = blockIdx.x;                 // [0, 2048)
    int q8 = id >> 7, rem = id & 127;
    int r  = rem >> 3, xx = rem & 7;
    int g  = q8*8 + xx;                  // [0, 128)
    int nlin = g*16 + r;                 // [0, 2048)
    int tt = 3 - (nlin >> 9);
    int h  = (nlin >> 6) & 7;
    int d  = nlin & 63;
    int hd = h*64 + d;
    int T0 = tt << 10;                   // 1024-row band per block

    int tid = threadIdx.x;
    const unsigned short* ga = arev + (size_t)hd*AREV_LEN;
    const unsigned int* g32 = (const unsigned int*)ga;
    unsigned int* l0 = (unsigned int*)lds;
    unsigned int* l1 = (unsigned int*)(lds + AREV_LEN);
    for (int i = tid; i < AREV_LEN/2; i += 256) l0[i] = g32[i];
    for (int i = tid; i < AREV_LEN/2 - 1; i += 256)
        l1[i] = (g32[i] >> 16) | (g32[i+1] << 16);   // arev[2i+1], arev[2i+2]
    __syncthreads();

    int w = tid >> 6, lane = tid & 63;
    int nb = lane & 15;        // A-frag row m and B-frag col n
    int q  = lane >> 4;        // k-quad
    int b  = T0 + 256*w + 16;  // low-col strip base; high cols land at b-16

    float4v acc[8];
    #pragma unroll
    for (int j = 0; j < 8; ++j) acc[j] = (float4v){0.f,0.f,0.f,0.f};

    // A addressing: i0(j, s0) = B0 - 32j + s0 + 8q; s0 even => parity lane-constant.
    int B0  = 4095 - b - nb;
    int ofs = B0 + 8*q;
    const unsigned int* lp =
        (const unsigned int*)(lds + ((ofs & 1) ? AREV_LEN : 0)) + (ofs >> 1);

    // B: cols 0-7 read x at s; cols 8-15 read x at s-16 (front pad covers s<16 -> 0)
    const unsigned short* xrow =
        xp + ((size_t)hd*BATCH + (nb & 7))*XPLEN + 16 - ((nb >> 3) << 4);

    auto LF = [&](int so) -> short8 {
        union { short8 v; unsigned int u[4]; } af;
        const unsigned int* p = lp + (so >> 1);
        af.u[0] = p[0]; af.u[1] = p[1]; af.u[2] = p[2]; af.u[3] = p[3];
        return af.v;
    };

    // ring: rg[p] holds frag(32*(p-8)) for p=1..7, rg[0] = frag(0)
    short8 rg[8];
    #pragma unroll
    for (int j = 1; j < 8; ++j) rg[8 - j] = LF(-32*j);
    rg[0] = LF(0);
    short8 bcur = *reinterpret_cast<const short8*>(xrow + 8*q);

    int s_end = b + 240;       // = T0 + 256w + 256: multiple of 256, covers max t

    for (int S = 0; S < s_end; S += 256) {
        #pragma unroll
        for (int u = 0; u < 8; ++u) {
            int so = S + 32*(u + 1);
            short8 rn = LF(so);                                          // prefetch A
            short8 bn = *reinterpret_cast<const short8*>(xrow + so + 8*q); // prefetch B
            #pragma unroll
            for (int j = 7; j >= 0; --j)
                acc[j] = __builtin_amdgcn_mfma_f32_16x16x32_bf16(
                    rg[(u - j) & 7], bcur, acc[j], 0, 0, 0);
            rg[(u + 1) & 7] = rn;   // slot freed by j=7 this step; pure renaming
            bcur = bn;
        }
    }

    // C/D: col = lane&15, row(t within 16) = 4q + rr; sub-tile j at base b+32j,
    // cols 8-15 shifted down 16 rows.
    int tsh = (nb >> 3) << 4;
    float* obase = out + ((size_t)((nb & 7)*H + h)*NSEQ)*DIM + d;
    #pragma unroll
    for (int j = 0; j < 8; ++j) {
        #pragma unroll
        for (int rr = 0; rr < 4; ++rr) {
            int t = b - tsh + 32*j + 4*q + rr;
            obase[(size_t)t*DIM] = acc[j][rr];
        }
    }
}

extern "C" void kernel_launch(void* const* d_in, const int* in_sizes, int n_in,
                              void* d_out, int out_size, void* d_ws, size_t ws_size,
                              hipStream_t stream) {
    const float* x     = (const float*)d_in[0];
    const float* zero  = (const float*)d_in[1];
    const float* pos   = (const float*)d_in[2];
    const float* gamma = (const float*)d_in[3];
    float* out = (float*)d_out;

    unsigned short* arev = (unsigned short*)d_ws;                 // 512*4384*2 = 4.49 MB
    unsigned short* xp   = arev + (size_t)HD*AREV_LEN;            // 512*8*4144*2 = 33.9 MB

    build_arev<<<dim3(64, 8), 256, 0, stream>>>(zero, pos, gamma, arev);
    build_xp<<<dim3(64, 8, 8), 256, 0, stream>>>(x, xp);
    toeplitz_gemm<<<dim3(2048), 256, 0, stream>>>(arev, xp, out);
}

// Round 2
// 249.162 us; speedup vs baseline: 1.3131x; 1.0029x over previous
//
#include <hip/hip_runtime.h>

#define H 8
#define NSEQ 4096
#define DIM 64
#define BATCH 8
#define AREV_LEN 4384   // 4096 lags + 288 zero pad (max read idx 4366). 4384 elems =
                        // 2192 dwords == 16 mod 32 -> lds1 sits at bank offset +16 vs
                        // lds0: parity groups hit disjoint bank halves.
#define XPLEN 4144      // 16 front zeros (shifted-col reads) + 4096 + 32 tail pad.
                        // 8288 B/row, 16B-aligned. Max read elem = 4111 (in-bounds).
#define HD (H*DIM)      // 512

typedef __attribute__((ext_vector_type(8))) short short8;
typedef __attribute__((ext_vector_type(4))) float float4v;

__device__ inline unsigned short f32_to_bf16(float f) {
    unsigned int u = __float_as_uint(f);
    u += 0x7fffu + ((u >> 16) & 1u);   // RNE
    return (unsigned short)(u >> 16);
}

// ---- P1: arev[hd][i] = bf16( exp(clamp(log(gamma)*k + pos[k-1])) ) at k = 4095 - i ----
// (k==0 uses `zero`). Block (kb,h) also zeroes the pad of row d=kb (replaces memset).
__global__ __launch_bounds__(256) void build_arev(
    const float* __restrict__ zero, const float* __restrict__ pos,
    const float* __restrict__ gamma, unsigned short* __restrict__ arev)
{
    __shared__ float lg[64];
    __shared__ unsigned short T[64][65];
    int h = blockIdx.y, kb = blockIdx.x;
    int tid = threadIdx.x;
    if (tid < 64) lg[tid] = logf(gamma[h*64 + tid]);
    __syncthreads();
    #pragma unroll
    for (int jj = 0; jj < 16; ++jj) {
        int e = tid + 256*jj;
        int kk = e >> 6, dd = e & 63;
        int k = kb*64 + kk;
        float v;
        if (k == 0) v = zero[h*64 + dd];
        else        v = lg[dd] * (float)k + pos[(h*4095 + (k-1))*64 + dd];
        v = fminf(30.f, fmaxf(-60.f, v));
        T[kk][dd] = f32_to_bf16(expf(v));
    }
    __syncthreads();
    int i0 = 4032 - kb*64;   // tile writes arev[hd][i0 .. i0+63], i = 4095 - k
    #pragma unroll
    for (int jj = 0; jj < 16; ++jj) {
        int e = tid + 256*jj;
        int dpr = e >> 6, ii = e & 63;
        arev[(size_t)(h*64 + dpr)*AREV_LEN + i0 + ii] = T[63 - ii][dpr];
    }
    // zero pad region [4096, AREV_LEN) of row d = kb
    unsigned short* pr = arev + (size_t)(h*64 + kb)*AREV_LEN + 4096;
    for (int i = tid; i < AREV_LEN - 4096; i += 256) pr[i] = 0;
}

// ---- P2: xp[hd][b][16 + s] = bf16(x[b][h][s][d]); rows front/tail zero-padded ----
__global__ __launch_bounds__(256) void build_xp(
    const float* __restrict__ x, unsigned short* __restrict__ xp)
{
    __shared__ unsigned short T[64][65];
    int sb = blockIdx.x, h = blockIdx.y, b = blockIdx.z;
    int tid = threadIdx.x;
    const float* src = x + ((size_t)(b*H + h)*NSEQ + sb*64)*DIM;
    #pragma unroll
    for (int jj = 0; jj < 16; ++jj) {
        int e = tid + 256*jj;
        int ss = e >> 6, dd = e & 63;
        T[ss][dd] = f32_to_bf16(src[ss*64 + dd]);
    }
    __syncthreads();
    #pragma unroll
    for (int jj = 0; jj < 16; ++jj) {
        int e = tid + 256*jj;
        int dpr = e >> 6, ii = e & 63;
        xp[((size_t)(h*64 + dpr)*BATCH + b)*XPLEN + 16 + sb*64 + ii] = T[ii][dpr];
    }
    if (sb == 0) {
        for (int e = tid; e < 64*16; e += 256) {
            int dd = e >> 4, i = e & 15;
            xp[((size_t)(h*64 + dd)*BATCH + b)*XPLEN + i] = 0;
        }
    }
    if (sb == 63) {
        for (int e = tid; e < 64*32; e += 256) {
            int dd = e >> 5, i = e & 31;
            xp[((size_t)(h*64 + dd)*BATCH + b)*XPLEN + 16 + NSEQ + i] = 0;
        }
    }
}

// ---- GEMM: per (h,d): Out[t, 0:8] = sum_s a[t-s] * X[s, 0:8], causal ----
// One WG = one (h,d) and a BAND PAIR {p, 3-p} of 1024-row t-bands (work of bands
// 0+3 == 1+2 == 544 k-steps, so ALL 1024 blocks and all waves do exactly 136
// k-steps: zero tail imbalance). Wave w runs lo-band tile w then hi-band tile
// 3-w (8(w+1) + 128-8w = 136 steps for p=0; 40+8w + 96-8w = 136 for p=1).
// MFMA cols 0-7 (x unshifted) give odd 16-row strips, cols 8-15 (x shifted -16
// via front pad) give even strips: all 16 columns useful. A-fragments rotate an
// 8-slot ring with compile-time indices (pure renaming); B uses a DEPTH-4
// register prefetch queue to cover L3 latency (~600 cyc) at 4 waves/SIMD.
__global__ __launch_bounds__(256) void toeplitz_gemm(
    const unsigned short* __restrict__ arev,
    const unsigned short* __restrict__ xp,
    float* __restrict__ out)
{
    __shared__ unsigned short lds[2*AREV_LEN];   // [0]: arev, [AREV_LEN]: arev shifted +1

    // swizzle: 16 line-sharing consecutive-d WGs -> same XCD (id%8).
    int id = blockIdx.x;                 // [0, 1024)
    int q8 = id >> 7, rem = id & 127;
    int r  = rem >> 3, xx = rem & 7;
    int g  = q8*8 + xx;                  // [0, 64)
    int nlin = g*16 + r;                 // [0, 1024)
    int p  = nlin >> 9;                  // band pair: {p, 3-p}
    int h  = (nlin >> 6) & 7;
    int d  = nlin & 63;
    int hd = h*64 + d;

    int tid = threadIdx.x;
    const unsigned short* ga = arev + (size_t)hd*AREV_LEN;
    const unsigned int* g32 = (const unsigned int*)ga;
    unsigned int* l0 = (unsigned int*)lds;
    unsigned int* l1 = (unsigned int*)(lds + AREV_LEN);
    int i0s = p << 9;                    // pair {1,2} never reads lag idx < 1024
    for (int i = i0s + tid; i < AREV_LEN/2; i += 256) l0[i] = g32[i];
    for (int i = i0s + tid; i < AREV_LEN/2 - 1; i += 256)
        l1[i] = (g32[i] >> 16) | (g32[i+1] << 16);   // arev[2i+1], arev[2i+2]
    __syncthreads();

    int w = tid >> 6, lane = tid & 63;
    int nb = lane & 15;        // A-frag row m and B-frag col n
    int q  = lane >> 4;        // k-quad

    // B row: cols 0-7 read x at s; cols 8-15 at s-16 (front pad covers s<16 -> 0)
    const unsigned short* xrow =
        xp + ((size_t)hd*BATCH + (nb & 7))*XPLEN + 16 - ((nb >> 3) << 4);
    int tsh = (nb >> 3) << 4;
    float* obase = out + ((size_t)((nb & 7)*H + h)*NSEQ)*DIM + d;

    auto run_phase = [&](int b) {
        float4v acc[8];
        #pragma unroll
        for (int j = 0; j < 8; ++j) acc[j] = (float4v){0.f,0.f,0.f,0.f};

        // A addressing: i0(j, s0) = B0 - 32j + s0 + 8q; s0 even => parity lane-const.
        int B0  = 4095 - b - nb;
        int ofs = B0 + 8*q;
        const unsigned int* lp =
            (const unsigned int*)(lds + ((ofs & 1) ? AREV_LEN : 0)) + (ofs >> 1);
        auto LF = [&](int so) -> short8 {
            union { short8 v; unsigned int u[4]; } af;
            const unsigned int* pp = lp + (so >> 1);
            af.u[0] = pp[0]; af.u[1] = pp[1]; af.u[2] = pp[2]; af.u[3] = pp[3];
            return af.v;
        };

        // ring: rg[j] holds frag for sub-tile chain; compile-time indices only
        short8 rg[8];
        #pragma unroll
        for (int j = 1; j < 8; ++j) rg[8 - j] = LF(-32*j);
        rg[0] = LF(0);

        int s_end = b + 240;   // multiple of 256

        // depth-4 B queue: bq[t&3] = B(32t)
        short8 bq[4];
        #pragma unroll
        for (int k = 0; k < 4; ++k)
            bq[k] = *reinterpret_cast<const short8*>(xrow + 32*k + 8*q);

        for (int S = 0; S < s_end; S += 256) {
            #pragma unroll
            for (int u = 0; u < 8; ++u) {
                int so = S + 32*u;
                short8 rn = LF(so + 32);                       // A prefetch (depth 1)
                int sp = so + 128;                             // B prefetch (depth 4)
                if (sp > s_end - 32) sp = 0;                   // wave-uniform clamp
                short8 bn = *reinterpret_cast<const short8*>(xrow + sp + 8*q);
                short8 bcur = bq[u & 3];
                #pragma unroll
                for (int j = 7; j >= 0; --j)
                    acc[j] = __builtin_amdgcn_mfma_f32_16x16x32_bf16(
                        rg[(u - j) & 7], bcur, acc[j], 0, 0, 0);
                rg[(u + 1) & 7] = rn;   // slot freed by j=7 this step; pure renaming
                bq[u & 3] = bn;
            }
        }

        // C/D: col = lane&15, row(t within 16) = 4q + rr; sub-tile j at base b+32j,
        // cols 8-15 shifted down 16 rows.
        #pragma unroll
        for (int j = 0; j < 8; ++j) {
            #pragma unroll
            for (int rr = 0; rr < 4; ++rr) {
                int t = b - tsh + 32*j + 4*q + rr;
                obase[(size_t)t*DIM] = acc[j][rr];
            }
        }
    };

    // pair {p, 3-p}: wave w takes lo tile w, hi tile 3-w  => 136 k-steps each
    run_phase((p << 10)       + 256*w       + 16);
    run_phase(((3 - p) << 10) + 256*(3 - w) + 16);
}

extern "C" void kernel_launch(void* const* d_in, const int* in_sizes, int n_in,
                              void* d_out, int out_size, void* d_ws, size_t ws_size,
                              hipStream_t stream) {
    const float* x     = (const float*)d_in[0];
    const float* zero  = (const float*)d_in[1];
    const float* pos   = (const float*)d_in[2];
    const float* gamma = (const float*)d_in[3];
    float* out = (float*)d_out;

    unsigned short* arev = (unsigned short*)d_ws;                 // 512*4384*2 = 4.49 MB
    unsigned short* xp   = arev + (size_t)HD*AREV_LEN;            // 512*8*4144*2 = 33.9 MB

    build_arev<<<dim3(64, 8), 256, 0, stream>>>(zero, pos, gamma, arev);
    build_xp<<<dim3(64, 8, 8), 256, 0, stream>>>(x, xp);
    toeplitz_gemm<<<dim3(1024), 256, 0, stream>>>(arev, xp, out);
}

// Round 3
// 247.681 us; speedup vs baseline: 1.3209x; 1.0060x over previous
//
#include <hip/hip_runtime.h>

#define H 8
#define NSEQ 4096
#define DIM 64
#define BATCH 8
#define AREV_LEN 4384   // 4096 lags + 288 zero pad (max read idx 4366). 4384 elems =
                        // 2192 dwords == 16 mod 32 -> shifted copy sits at bank
                        // offset +16 vs base copy: parity groups hit disjoint halves.
#define AREV_DW (AREV_LEN/2)   // 2192
#define XPLEN 4144      // 16 front zeros (shifted-col reads) + 4096 + 32 tail pad.
                        // 8288 B/row, 16B-aligned. Max read elem = 4111 (in-bounds).
#define HD (H*DIM)      // 512

typedef __attribute__((ext_vector_type(8))) short short8;
typedef __attribute__((ext_vector_type(4))) float float4v;

__device__ inline unsigned short f32_to_bf16(float f) {
    unsigned int u = __float_as_uint(f);
    u += 0x7fffu + ((u >> 16) & 1u);   // RNE
    return (unsigned short)(u >> 16);
}

// ---- P1: arev[hd][i] = bf16( exp(clamp(log(gamma)*k + pos[k-1])) ) at k = 4095 - i ----
// (k==0 uses `zero`). Block (kb,h) also zeroes the pad of row d=kb (replaces memset).
__global__ __launch_bounds__(256) void build_arev(
    const float* __restrict__ zero, const float* __restrict__ pos,
    const float* __restrict__ gamma, unsigned short* __restrict__ arev)
{
    __shared__ float lg[64];
    __shared__ unsigned short T[64][65];
    int h = blockIdx.y, kb = blockIdx.x;
    int tid = threadIdx.x;
    if (tid < 64) lg[tid] = logf(gamma[h*64 + tid]);
    __syncthreads();
    #pragma unroll
    for (int jj = 0; jj < 16; ++jj) {
        int e = tid + 256*jj;
        int kk = e >> 6, dd = e & 63;
        int k = kb*64 + kk;
        float v;
        if (k == 0) v = zero[h*64 + dd];
        else        v = lg[dd] * (float)k + pos[(h*4095 + (k-1))*64 + dd];
        v = fminf(30.f, fmaxf(-60.f, v));
        T[kk][dd] = f32_to_bf16(expf(v));
    }
    __syncthreads();
    int i0 = 4032 - kb*64;   // tile writes arev[hd][i0 .. i0+63], i = 4095 - k
    #pragma unroll
    for (int jj = 0; jj < 16; ++jj) {
        int e = tid + 256*jj;
        int dpr = e >> 6, ii = e & 63;
        arev[(size_t)(h*64 + dpr)*AREV_LEN + i0 + ii] = T[63 - ii][dpr];
    }
    // zero pad region [4096, AREV_LEN) of row d = kb
    unsigned short* pr = arev + (size_t)(h*64 + kb)*AREV_LEN + 4096;
    for (int i = tid; i < AREV_LEN - 4096; i += 256) pr[i] = 0;
}

// ---- P2: xp[hd][b][16 + s] = bf16(x[b][h][s][d]); rows front/tail zero-padded ----
// float4 global loads, dword-packed global stores.
__global__ __launch_bounds__(256) void build_xp(
    const float* __restrict__ x, unsigned short* __restrict__ xp)
{
    __shared__ unsigned short T[64][66];   // stride 66: dword-aligned cols, no read conflicts
    int sb = blockIdx.x, h = blockIdx.y, b = blockIdx.z;
    int tid = threadIdx.x;
    const float4v* src4 =
        (const float4v*)(x + ((size_t)(b*H + h)*NSEQ + sb*64)*DIM);
    #pragma unroll
    for (int jj = 0; jj < 4; ++jj) {
        int e = tid + 256*jj;            // [0,1024)
        int ss = e >> 4, d4 = e & 15;
        float4v f = src4[ss*16 + d4];
        #pragma unroll
        for (int k = 0; k < 4; ++k) T[ss][4*d4 + k] = f32_to_bf16(f[k]);
    }
    __syncthreads();
    unsigned int* xp32 = (unsigned int*)xp;
    #pragma unroll
    for (int jj = 0; jj < 8; ++jj) {
        int e = tid + 256*jj;            // [0,2048)
        int dpr = e >> 5, c2 = e & 31;   // row d, dword col (2 s-elems)
        unsigned int lo = T[2*c2][dpr], hi = T[2*c2 + 1][dpr];
        size_t dwofs = (((size_t)(h*64 + dpr)*BATCH + b)*XPLEN + 16 + sb*64) >> 1;
        xp32[dwofs + c2] = lo | (hi << 16);
    }
    if (sb == 0) {
        for (int e = tid; e < 64*16; e += 256) {
            int dd = e >> 4, i = e & 15;
            xp[((size_t)(h*64 + dd)*BATCH + b)*XPLEN + i] = 0;
        }
    }
    if (sb == 63) {
        for (int e = tid; e < 64*32; e += 256) {
            int dd = e >> 5, i = e & 31;
            xp[((size_t)(h*64 + dd)*BATCH + b)*XPLEN + 16 + NSEQ + i] = 0;
        }
    }
}

// ---- GEMM: per (h,d): Out[t, 0:8] = sum_s a[t-s] * X[s, 0:8], causal ----
// One WG = one (h,d) and a BAND PAIR {p, 3-p} of 1024-row t-bands; every wave
// does exactly 136 k-steps (zero imbalance). MFMA cols 0-7 (x unshifted) give
// odd 16-row strips, cols 8-15 (x shifted -16 via front pad) give even strips.
// A-ring with compile-time indices; depth-4 B register queue.
// LDS is a native dword array indexed DIRECTLY (no casted pointers) so the
// compiler provably emits ds_read_b32/ds_write_b32, never flat_*.
__global__ __launch_bounds__(256) void toeplitz_gemm(
    const unsigned short* __restrict__ arev,
    const unsigned short* __restrict__ xp,
    float* __restrict__ out)
{
    __shared__ unsigned int lds32[2*AREV_DW];  // [0]: arev dwords, [AREV_DW]: +1-elem shift

    // swizzle: 16 line-sharing consecutive-d WGs -> same XCD (id%8).
    int id = blockIdx.x;                 // [0, 1024)
    int q8 = id >> 7, rem = id & 127;
    int r  = rem >> 3, xx = rem & 7;
    int g  = q8*8 + xx;                  // [0, 64)
    int nlin = g*16 + r;                 // [0, 1024)
    int p  = nlin >> 9;                  // band pair: {p, 3-p}
    int h  = (nlin >> 6) & 7;
    int d  = nlin & 63;
    int hd = h*64 + d;

    int tid = threadIdx.x;
    const unsigned int* g32 = (const unsigned int*)(arev + (size_t)hd*AREV_LEN);
    int i0s = p << 9;                    // pair {1,2} never reads lag idx < 1024
    for (int i = i0s + tid; i < AREV_DW; i += 256) lds32[i] = g32[i];
    for (int i = i0s + tid; i < AREV_DW - 1; i += 256)
        lds32[AREV_DW + i] = (g32[i] >> 16) | (g32[i+1] << 16);  // elems 2i+1, 2i+2
    __syncthreads();

    int w = tid >> 6, lane = tid & 63;
    int nb = lane & 15;        // A-frag row m and B-frag col n
    int q  = lane >> 4;        // k-quad

    // B row: cols 0-7 read x at s; cols 8-15 at s-16 (front pad covers s<16 -> 0)
    const unsigned short* xrow =
        xp + ((size_t)hd*BATCH + (nb & 7))*XPLEN + 16 - ((nb >> 3) << 4);
    int tsh = (nb >> 3) << 4;
    float* obase = out + ((size_t)((nb & 7)*H + h)*NSEQ)*DIM + d;

    auto run_phase = [&](int b) {
        float4v acc[8];
        #pragma unroll
        for (int j = 0; j < 8; ++j) acc[j] = (float4v){0.f,0.f,0.f,0.f};

        // A addressing: elem i0(j, s0) = B0 - 32j + s0 + 8q; s0 even => parity
        // is lane-constant: pick base copy (even) or +1-shift copy (odd) once.
        int B0  = 4095 - b - nb;
        int ofs = B0 + 8*q;
        int dwb = ((ofs & 1) ? AREV_DW : 0) + (ofs >> 1);
        auto LF = [&](int so) -> short8 {
            int dw = dwb + (so >> 1);    // so always even
            union { short8 v; unsigned int u[4]; } af;
            af.u[0] = lds32[dw];   af.u[1] = lds32[dw+1];
            af.u[2] = lds32[dw+2]; af.u[3] = lds32[dw+3];
            return af.v;
        };

        // ring: compile-time indices only (pure register renaming)
        short8 rg[8];
        #pragma unroll
        for (int j = 1; j < 8; ++j) rg[8 - j] = LF(-32*j);
        rg[0] = LF(0);

        int s_end = b + 240;   // multiple of 256

        // depth-4 B queue: bq[t&3] = B(32t)
        short8 bq[4];
        #pragma unroll
        for (int k = 0; k < 4; ++k)
            bq[k] = *reinterpret_cast<const short8*>(xrow + 32*k + 8*q);

        for (int S = 0; S < s_end; S += 256) {
            #pragma unroll
            for (int u = 0; u < 8; ++u) {
                int so = S + 32*u;
                short8 rn = LF(so + 32);                       // A prefetch (depth 1)
                int sp = so + 128;                             // B prefetch (depth 4)
                if (sp > s_end - 32) sp = 0;                   // wave-uniform clamp
                short8 bn = *reinterpret_cast<const short8*>(xrow + sp + 8*q);
                short8 bcur = bq[u & 3];
                #pragma unroll
                for (int j = 7; j >= 0; --j)
                    acc[j] = __builtin_amdgcn_mfma_f32_16x16x32_bf16(
                        rg[(u - j) & 7], bcur, acc[j], 0, 0, 0);
                rg[(u + 1) & 7] = rn;   // slot freed by j=7 this step
                bq[u & 3] = bn;
            }
        }

        // C/D: col = lane&15, row(t within 16) = 4q + rr; sub-tile j at base b+32j,
        // cols 8-15 shifted down 16 rows.
        #pragma unroll
        for (int j = 0; j < 8; ++j) {
            #pragma unroll
            for (int rr = 0; rr < 4; ++rr) {
                int t = b - tsh + 32*j + 4*q + rr;
                obase[(size_t)t*DIM] = acc[j][rr];
            }
        }
    };

    // pair {p, 3-p}: wave w takes lo tile w, hi tile 3-w  => 136 k-steps each
    run_phase((p << 10)       + 256*w       + 16);
    run_phase(((3 - p) << 10) + 256*(3 - w) + 16);
}

extern "C" void kernel_launch(void* const* d_in, const int* in_sizes, int n_in,
                              void* d_out, int out_size, void* d_ws, size_t ws_size,
                              hipStream_t stream) {
    const float* x     = (const float*)d_in[0];
    const float* zero  = (const float*)d_in[1];
    const float* pos   = (const float*)d_in[2];
    const float* gamma = (const float*)d_in[3];
    float* out = (float*)d_out;

    unsigned short* arev = (unsigned short*)d_ws;                 // 512*4384*2 = 4.49 MB
    unsigned short* xp   = arev + (size_t)HD*AREV_LEN;            // 512*8*4144*2 = 33.9 MB

    build_arev<<<dim3(64, 8), 256, 0, stream>>>(zero, pos, gamma, arev);
    build_xp<<<dim3(64, 8, 8), 256, 0, stream>>>(x, xp);
    toeplitz_gemm<<<dim3(1024), 256, 0, stream>>>(arev, xp, out);
}